// Round 1
// baseline (836.535 us; speedup 1.0000x reference)
//
#include <hip/hip_runtime.h>

// Attention4D: B=64, DIM=384, RES=14 (N=196), NH=8, KD=32, DV=128
// Round 1: correct fp32 implementation, tiled vector-ALU GEMMs.
// Workspace layout (floats): qt 3.2M | kmat 3.2M | vt 12.8M | vlt 12.8M |
//   attn 19.7M | ot 12.8M  -> total 64,626,688 floats = 258.5 MB

#define RES   14
#define NSP   196
#define BATCH 64
#define DIM   384
#define NHD   8
#define KDIM  32
#define DVV   128
#define NQK   256
#define NV    1024
#define NOFF  196
#define SCALE 0.17677669529663687f

// ---------------- K1: fused QKV projection ----------------
// GEMM: Out[oc, m] = sum_c W[oc,c] * x[b(m), c, n(m)],  M = B*NSP = 12544
// grid (98, 12): blockIdx.x = m-tile(128), blockIdx.y = oc-tile(128) of 1536
// outputs: qt (B,NSP,256)  kmat (B,256,NSP)  vt (B,NH,NSP,DV)
__global__ __launch_bounds__(256) void k_qkv(
    const float* __restrict__ x,
    const float* __restrict__ qw, const float* __restrict__ qb,
    const float* __restrict__ kw, const float* __restrict__ kb,
    const float* __restrict__ vw, const float* __restrict__ vb,
    float* __restrict__ qt, float* __restrict__ kmat, float* __restrict__ vt)
{
    __shared__ float Xs[16][128];
    __shared__ float Ws[128][17];   // +1 pad: kills 4-way bank conflict
    const int tid = threadIdx.x;
    const int m0 = blockIdx.x * 128;
    const int octile = blockIdx.y;

    const float* wsel; const float* bsel; int row0; int sect;
    if (octile < 2)      { wsel = qw; bsel = qb; row0 = octile * 128;       sect = 0; }
    else if (octile < 4) { wsel = kw; bsel = kb; row0 = (octile - 2) * 128; sect = 1; }
    else                 { wsel = vw; bsel = vb; row0 = (octile - 4) * 128; sect = 2; }

    const int to = tid >> 4;   // 0..15 -> oc_l = to*8+j
    const int tm = tid & 15;   // m_l = tm + 16*i

    // X loader: column fixed per thread
    const int mmL  = tid & 127;
    const int kk0L = tid >> 7;      // kk = kk0L + 2*l
    const int mL = m0 + mmL;
    const int bL = mL / NSP;
    const int nL = mL - bL * NSP;
    const long xbase = (long)bL * DIM * NSP + nL;
    // W loader
    const int rL  = tid >> 4;
    const int kkL = tid & 15;

    float acc[8][8];
    #pragma unroll
    for (int j = 0; j < 8; ++j)
        #pragma unroll
        for (int i = 0; i < 8; ++i) acc[j][i] = 0.f;

    for (int k0 = 0; k0 < DIM; k0 += 16) {
        #pragma unroll
        for (int l = 0; l < 8; ++l) {
            int kk = kk0L + 2 * l;
            Xs[kk][mmL] = x[xbase + (long)(k0 + kk) * NSP];
        }
        #pragma unroll
        for (int l = 0; l < 8; ++l) {
            int r = rL + 16 * l;
            Ws[r][kkL] = wsel[(long)(row0 + r) * DIM + k0 + kkL];
        }
        __syncthreads();
        #pragma unroll
        for (int kk = 0; kk < 16; ++kk) {
            float xv[8], wv[8];
            #pragma unroll
            for (int i = 0; i < 8; ++i) xv[i] = Xs[kk][tm + 16 * i];
            #pragma unroll
            for (int j = 0; j < 8; ++j) wv[j] = Ws[to * 8 + j][kk];
            #pragma unroll
            for (int j = 0; j < 8; ++j)
                #pragma unroll
                for (int i = 0; i < 8; ++i)
                    acc[j][i] += wv[j] * xv[i];
        }
        __syncthreads();
    }

    float bias[8];
    #pragma unroll
    for (int j = 0; j < 8; ++j) bias[j] = bsel[row0 + to * 8 + j];

    #pragma unroll
    for (int i = 0; i < 8; ++i) {
        int m = m0 + tm + 16 * i;
        int b = m / NSP;
        int n = m - b * NSP;
        float v0[8];
        #pragma unroll
        for (int j = 0; j < 8; ++j) v0[j] = acc[j][i] + bias[j];
        if (sect == 0) {
            float* p = &qt[(long)(b * NSP + n) * NQK + row0 + to * 8];
            *(float4*)p       = make_float4(v0[0], v0[1], v0[2], v0[3]);
            *(float4*)(p + 4) = make_float4(v0[4], v0[5], v0[6], v0[7]);
        } else if (sect == 1) {
            #pragma unroll
            for (int j = 0; j < 8; ++j)
                kmat[((long)b * NQK + row0 + to * 8 + j) * NSP + n] = v0[j];
        } else {
            float* p = &vt[((long)(b * NHD + (row0 >> 7)) * NSP + n) * DVV + to * 8];
            *(float4*)p       = make_float4(v0[0], v0[1], v0[2], v0[3]);
            *(float4*)(p + 4) = make_float4(v0[4], v0[5], v0[6], v0[7]);
        }
    }
}

// ---------------- K2: depthwise 3x3 conv on vt layout ----------------
__global__ __launch_bounds__(256) void k_dwconv(
    const float* __restrict__ vt, const float* __restrict__ vlw,
    const float* __restrict__ vlb, float* __restrict__ vlt)
{
    int f = blockIdx.x * 256 + threadIdx.x;     // (bh, n, d), d minor
    int d  = f & (DVV - 1);
    int t  = f >> 7;
    int n  = t % NSP;
    int bh = t / NSP;
    int h  = bh & 7;
    int y  = n / RES, xx = n - y * RES;
    int ch = h * DVV + d;
    float sacc = vlb[ch];
    const float* wp = vlw + ch * 9;
    const float* vp = vt + (long)bh * NSP * DVV + d;
    #pragma unroll
    for (int dy = -1; dy <= 1; ++dy) {
        int yy = y + dy;
        if (yy < 0 || yy >= RES) continue;
        #pragma unroll
        for (int dx = -1; dx <= 1; ++dx) {
            int xn = xx + dx;
            if (xn < 0 || xn >= RES) continue;
            sacc += wp[(dy + 1) * 3 + (dx + 1)] * vp[(yy * RES + xn) * DVV];
        }
    }
    vlt[f] = sacc;
}

// ---------------- K3: scores + bias + th1 + softmax + th2 ----------------
// block = (b, 4 consecutive n rows), all 8 heads resident in LDS
__global__ __launch_bounds__(256) void k_attn(
    const float* __restrict__ qt, const float* __restrict__ kmat,
    const float* __restrict__ bias_seg, const int* __restrict__ bias_idxs,
    const float* __restrict__ th1w, const float* __restrict__ th1b,
    const float* __restrict__ th2w, const float* __restrict__ th2b,
    float* __restrict__ attn)
{
    __shared__ float qs[4][NQK];
    __shared__ float s[4 * NHD][NSP];   // [np*8+h][m]
    __shared__ float w1[64], w2[64], b1v[8], b2v[8];
    const int tid = threadIdx.x;
    const int b  = blockIdx.y;
    const int n0 = blockIdx.x * 4;

    if (tid < 64) w1[tid] = th1w[tid];
    else if (tid < 128) w2[tid - 64] = th2w[tid - 64];
    else if (tid < 136) b1v[tid - 128] = th1b[tid - 128];
    else if (tid < 144) b2v[tid - 136] = th2b[tid - 136];

    #pragma unroll
    for (int l = 0; l < 4; ++l) {
        int idx = tid + l * 256;
        int np = idx >> 8, c = idx & 255;
        qs[np][c] = qt[(long)(b * NSP + n0 + np) * NQK + c];
    }
    __syncthreads();

    // phase A: raw scores * SCALE + rel-pos bias
    for (int jj = tid; jj < NHD * NSP; jj += 256) {
        int h = jj / NSP;
        int m = jj - h * NSP;
        const float* kcol = kmat + ((long)b * NQK + h * KDIM) * NSP + m;
        float d0 = 0.f, d1 = 0.f, d2 = 0.f, d3 = 0.f;
        #pragma unroll
        for (int kd = 0; kd < KDIM; ++kd) {
            float kv = kcol[(long)kd * NSP];
            d0 += qs[0][h * KDIM + kd] * kv;
            d1 += qs[1][h * KDIM + kd] * kv;
            d2 += qs[2][h * KDIM + kd] * kv;
            d3 += qs[3][h * KDIM + kd] * kv;
        }
        const float* bsh = bias_seg + h * NOFF;
        s[h][m]      = d0 * SCALE + bsh[bias_idxs[(n0 + 0) * NSP + m]];
        s[8 + h][m]  = d1 * SCALE + bsh[bias_idxs[(n0 + 1) * NSP + m]];
        s[16 + h][m] = d2 * SCALE + bsh[bias_idxs[(n0 + 2) * NSP + m]];
        s[24 + h][m] = d3 * SCALE + bsh[bias_idxs[(n0 + 3) * NSP + m]];
    }
    __syncthreads();

    // phase B: talking-heads 1 (in place: load-all, barrier, write-all)
    float regs[4][8];
    {
        int cnt = 0;
        for (int p = tid; p < 4 * NSP; p += 256) {
            int np = p / NSP, m = p - np * NSP;
            #pragma unroll
            for (int g = 0; g < 8; ++g) regs[cnt][g] = s[np * 8 + g][m];
            ++cnt;
        }
        __syncthreads();
        cnt = 0;
        for (int p = tid; p < 4 * NSP; p += 256) {
            int np = p / NSP, m = p - np * NSP;
            #pragma unroll
            for (int h = 0; h < 8; ++h) {
                float a = b1v[h];
                #pragma unroll
                for (int g = 0; g < 8; ++g) a += w1[h * 8 + g] * regs[cnt][g];
                s[np * 8 + h][m] = a;
            }
            ++cnt;
        }
    }
    __syncthreads();

    // phase C: softmax over m, one wave per row
    {
        const int wave = tid >> 6, lane = tid & 63;
        for (int r = wave; r < 32; r += 4) {
            float* row = s[r];
            float mx = -1e30f;
            for (int m = lane; m < NSP; m += 64) mx = fmaxf(mx, row[m]);
            #pragma unroll
            for (int off = 32; off; off >>= 1) mx = fmaxf(mx, __shfl_xor(mx, off));
            float sum = 0.f;
            for (int m = lane; m < NSP; m += 64) {
                float e = __expf(row[m] - mx);
                row[m] = e;
                sum += e;
            }
            #pragma unroll
            for (int off = 32; off; off >>= 1) sum += __shfl_xor(sum, off);
            float inv = 1.0f / sum;
            for (int m = lane; m < NSP; m += 64) row[m] *= inv;
        }
    }
    __syncthreads();

    // phase D: talking-heads 2 + store attn (B,NH,NSP,NSP)
    for (int p = tid; p < 4 * NSP; p += 256) {
        int np = p / NSP, m = p - np * NSP;
        float pg[8];
        #pragma unroll
        for (int g = 0; g < 8; ++g) pg[g] = s[np * 8 + g][m];
        #pragma unroll
        for (int h = 0; h < 8; ++h) {
            float a = b2v[h];
            #pragma unroll
            for (int g = 0; g < 8; ++g) a += w2[h * 8 + g] * pg[g];
            attn[(((long)b * NHD + h) * NSP + n0 + np) * NSP + m] = a;
        }
    }
}

// ---------------- K4: O = attn @ V, + v_local, ReLU ----------------
// per (b,h): C[n,d] = sum_m A[n,m] * Vt[m,d]; tile 32n x 128d, K-chunk 28
__global__ __launch_bounds__(256) void k_av(
    const float* __restrict__ attn, const float* __restrict__ vt,
    const float* __restrict__ vlt, float* __restrict__ ot)
{
    __shared__ float As[28][36];     // [kk][n_l], pad 36
    __shared__ float Vs[28][DVV];    // [kk][d]
    const int tid = threadIdx.x;
    const int bh = blockIdx.y;             // b*8+h
    const int n0 = blockIdx.x * 32;        // 7 tiles (224 >= 196)
    const int td = tid & 31, tn = tid >> 5;
    const long abase = (long)bh * NSP * NSP;
    const long vbase = (long)bh * NSP * DVV;
    float acc[4][4];
    #pragma unroll
    for (int i = 0; i < 4; ++i)
        #pragma unroll
        for (int j = 0; j < 4; ++j) acc[i][j] = 0.f;

    for (int m0 = 0; m0 < NSP; m0 += 28) {
        for (int idx = tid; idx < 32 * 28; idx += 256) {
            int nr = idx / 28, kk = idx - nr * 28;
            float val = 0.f;
            if (n0 + nr < NSP) val = attn[abase + (long)(n0 + nr) * NSP + m0 + kk];
            As[kk][nr] = val;
        }
        #pragma unroll
        for (int l = 0; l < 14; ++l) {
            int idx = tid + l * 256;
            int kk = idx >> 7, d = idx & 127;
            Vs[kk][d] = vt[vbase + (long)(m0 + kk) * DVV + d];
        }
        __syncthreads();
        #pragma unroll
        for (int kk = 0; kk < 28; ++kk) {
            float4 a4 = *(const float4*)&As[kk][tn * 4];
            float4 v4 = *(const float4*)&Vs[kk][td * 4];
            float av[4] = {a4.x, a4.y, a4.z, a4.w};
            float vv[4] = {v4.x, v4.y, v4.z, v4.w};
            #pragma unroll
            for (int i = 0; i < 4; ++i)
                #pragma unroll
                for (int j = 0; j < 4; ++j)
                    acc[i][j] += av[i] * vv[j];
        }
        __syncthreads();
    }

    #pragma unroll
    for (int i = 0; i < 4; ++i) {
        int n = n0 + tn * 4 + i;
        if (n < NSP) {
            long off = vbase + (long)n * DVV + td * 4;
            float4 vl = *(const float4*)&vlt[off];
            float4 r;
            r.x = fmaxf(acc[i][0] + vl.x, 0.f);
            r.y = fmaxf(acc[i][1] + vl.y, 0.f);
            r.z = fmaxf(acc[i][2] + vl.z, 0.f);
            r.w = fmaxf(acc[i][3] + vl.w, 0.f);
            *(float4*)&ot[off] = r;
        }
    }
}

// ---------------- K5: output projection ----------------
// out[b,oc,n] = projb[oc] + sum_c projw[oc,c] * ot[b, c/128, n, c%128]
// grid (98, 6): m-tile 128, oc-tile 64
__global__ __launch_bounds__(256) void k_proj(
    const float* __restrict__ ot, const float* __restrict__ projw,
    const float* __restrict__ projb, float* __restrict__ outp)
{
    __shared__ float Xs[16][132];    // pad 132: 2-way max on c-minor store
    __shared__ float Ws[64][17];
    const int tid = threadIdx.x;
    const int m0  = blockIdx.x * 128;
    const int oc0 = blockIdx.y * 64;
    const int to = tid >> 4, tm = tid & 15;   // oc_l = to*4+j, m_l = tm+16i
    const int kkL  = tid & 15;
    const int mmL0 = tid >> 4;
    int bLs[8], nLs[8];
    #pragma unroll
    for (int l = 0; l < 8; ++l) {
        int m = m0 + mmL0 + 16 * l;
        bLs[l] = m / NSP; nLs[l] = m - bLs[l] * NSP;
    }
    float acc[4][8];
    #pragma unroll
    for (int j = 0; j < 4; ++j)
        #pragma unroll
        for (int i = 0; i < 8; ++i) acc[j][i] = 0.f;

    for (int k0 = 0; k0 < NV; k0 += 16) {
        const int h = k0 >> 7;
        const int dsel = (k0 & 127) + kkL;
        #pragma unroll
        for (int l = 0; l < 8; ++l) {
            Xs[kkL][mmL0 + 16 * l] =
                ot[((long)(bLs[l] * NHD + h) * NSP + nLs[l]) * DVV + dsel];
        }
        #pragma unroll
        for (int l = 0; l < 4; ++l) {
            int r = (tid >> 4) + 16 * l;
            Ws[r][kkL] = projw[(long)(oc0 + r) * NV + k0 + kkL];
        }
        __syncthreads();
        #pragma unroll
        for (int kk = 0; kk < 16; ++kk) {
            float xv[8], wv[4];
            #pragma unroll
            for (int i = 0; i < 8; ++i) xv[i] = Xs[kk][tm + 16 * i];
            #pragma unroll
            for (int j = 0; j < 4; ++j) wv[j] = Ws[to * 4 + j][kk];
            #pragma unroll
            for (int j = 0; j < 4; ++j)
                #pragma unroll
                for (int i = 0; i < 8; ++i)
                    acc[j][i] += wv[j] * xv[i];
        }
        __syncthreads();
    }

    #pragma unroll
    for (int i = 0; i < 8; ++i) {
        int m = m0 + tm + 16 * i;
        int b = m / NSP, n = m - b * NSP;
        #pragma unroll
        for (int j = 0; j < 4; ++j) {
            int oc = oc0 + to * 4 + j;
            outp[((long)b * DIM + oc) * NSP + n] = acc[j][i] + projb[oc];
        }
    }
}

extern "C" void kernel_launch(void* const* d_in, const int* in_sizes, int n_in,
                              void* d_out, int out_size, void* d_ws, size_t ws_size,
                              hipStream_t stream) {
    const float* x        = (const float*)d_in[0];
    const float* qw       = (const float*)d_in[1];
    const float* qb       = (const float*)d_in[2];
    const float* kw       = (const float*)d_in[3];
    const float* kb       = (const float*)d_in[4];
    const float* vw       = (const float*)d_in[5];
    const float* vb       = (const float*)d_in[6];
    const float* vlw      = (const float*)d_in[7];
    const float* vlb      = (const float*)d_in[8];
    const float* th1w     = (const float*)d_in[9];
    const float* th1b     = (const float*)d_in[10];
    const float* th2w     = (const float*)d_in[11];
    const float* th2b     = (const float*)d_in[12];
    const float* projw    = (const float*)d_in[13];
    const float* projb    = (const float*)d_in[14];
    const float* bias_seg = (const float*)d_in[15];
    const int*   bias_idx = (const int*)d_in[16];
    float* outp = (float*)d_out;

    float* ws   = (float*)d_ws;
    float* qt   = ws;                    // (B,NSP,NQK)      3,211,264
    float* kmat = qt   + 3211264;        // (B,NQK,NSP)      3,211,264
    float* vt   = kmat + 3211264;        // (B,NH,NSP,DV)   12,845,056
    float* vlt  = vt   + 12845056;       // (B,NH,NSP,DV)   12,845,056
    float* attn = vlt  + 12845056;       // (B,NH,NSP,NSP)  19,668,992
    float* ot   = attn + 19668992;       // (B,NH,NSP,DV)   12,845,056
    // end: 64,626,688 floats = 258.5 MB <= ws_size (assumed)

    k_qkv<<<dim3(98, 12), 256, 0, stream>>>(x, qw, qb, kw, kb, vw, vb, qt, kmat, vt);
    k_dwconv<<<dim3(50176), 256, 0, stream>>>(vt, vlw, vlb, vlt);
    k_attn<<<dim3(49, 64), 256, 0, stream>>>(qt, kmat, bias_seg, bias_idx,
                                             th1w, th1b, th2w, th2b, attn);
    k_av<<<dim3(7, 512), 256, 0, stream>>>(attn, vt, vlt, ot);
    k_proj<<<dim3(98, 6), 256, 0, stream>>>(ot, projw, projb, outp);
}

// Round 3
// 475.759 us; speedup vs baseline: 1.7583x; 1.7583x over previous
//
#include <hip/hip_runtime.h>
#include <hip/hip_bf16.h>

// Attention4D MI355X round 3: round-2 MFMA pipeline + fixed k_prep_w splits
// (qw/kw are 256x384 = 98304 elements each, NOT 196608).
// B=64, DIM=384, N=196 (14x14), NH=8, KD=32, DV=128.

#define RES   14
#define NSP   196
#define NHD   8
#define KDIM  32
#define DVV   128
#define DIM   384
#define NQK   256
#define SCALE 0.17677669529663687f

typedef __attribute__((ext_vector_type(8))) short bf16x8;
typedef __attribute__((ext_vector_type(4))) float f32x4;
typedef unsigned short u16;

__device__ __forceinline__ u16 f2b(float f) {
    union { __hip_bfloat16 b; u16 u; } c; c.b = __float2bfloat16(f); return c.u;
}
__device__ __forceinline__ float b2f(u16 u) {
    union { __hip_bfloat16 b; u16 u; } c; c.u = u; return __bfloat162float(c.b);
}

// async global->LDS, 16B per lane; LDS dest = wave-uniform base + lane*16
__device__ __forceinline__ void gld16(const void* g, void* l) {
    __builtin_amdgcn_global_load_lds(
        (__attribute__((address_space(1))) void*)(unsigned long long)(const char*)g,
        (__attribute__((address_space(3))) void*)l, 16, 0, 0);
}

// ---- shared 128x128 bf16 MFMA GEMM core (m97 structure) ----
// A: 128 rows (M), k-major, row stride rbA bytes. B: 128 rows (N), k-major.
// Each k-iter consumes K=32 (64 B per row). acc[i][j]: frag (m=i*16, n=j*16)
// within the wave's 64x64 quadrant; wave quadrant: wm=(wid&1)*64, wn=(wid>>1)*64.
__device__ __forceinline__ void gemm128(const char* Aseg, long rbA,
                                        const char* Bseg, long rbB, int kIters,
                                        u16* A_lds, u16* B_lds, f32x4 acc[4][4])
{
    const int tid  = threadIdx.x;
    const int wid  = tid >> 6;
    const int lane = tid & 63;
    const int lrow = lane >> 2;          // 0..15 rows within a 16-row chunk
    const int lcb  = (lane & 3) << 4;    // byte offset within 64-B row
    const int r0   = wid * 32;           // this wave stages rows r0..r0+31 of A and B
    const int wm   = (wid & 1) * 64, wn = (wid >> 1) * 64;
    const int l15  = lane & 15, lq8 = (lane >> 4) * 8;

    #pragma unroll
    for (int i = 0; i < 4; ++i)
        #pragma unroll
        for (int j = 0; j < 4; ++j) acc[i][j] = (f32x4){0.f, 0.f, 0.f, 0.f};

    const char* ap0 = Aseg + (long)(r0 + lrow) * rbA + lcb;
    const char* ap1 = ap0 + 16 * rbA;
    const char* bp0 = Bseg + (long)(r0 + lrow) * rbB + lcb;
    const char* bp1 = bp0 + 16 * rbB;
    u16* la0 = A_lds + r0 * 32;
    u16* la1 = A_lds + (r0 + 16) * 32;
    u16* lb0 = B_lds + r0 * 32;
    u16* lb1 = B_lds + (r0 + 16) * 32;

    for (int kk = 0; kk < kIters; ++kk) {
        gld16(ap0, la0); gld16(ap1, la1);
        gld16(bp0, lb0); gld16(bp1, lb1);
        ap0 += 64; ap1 += 64; bp0 += 64; bp1 += 64;
        __syncthreads();   // drains vmcnt(0) then barrier
        bf16x8 af[4], bfr[4];
        #pragma unroll
        for (int i = 0; i < 4; ++i)
            af[i] = *(const bf16x8*)&A_lds[(wm + i * 16 + l15) * 32 + lq8];
        #pragma unroll
        for (int j = 0; j < 4; ++j)
            bfr[j] = *(const bf16x8*)&B_lds[(wn + j * 16 + l15) * 32 + lq8];
        #pragma unroll
        for (int i = 0; i < 4; ++i)
            #pragma unroll
            for (int j = 0; j < 4; ++j)
                acc[i][j] = __builtin_amdgcn_mfma_f32_16x16x32_bf16(
                    af[i], bfr[j], acc[i][j], 0, 0, 0);
        __syncthreads();
    }
}

// ---------------- prep: weights fp32 -> bf16 ----------------
// qw: 256*384=98304, kw: 98304, vw: 1024*384=393216, projw: 384*1024=393216
__global__ __launch_bounds__(256) void k_prep_w(
    const float* __restrict__ qw, const float* __restrict__ kw,
    const float* __restrict__ vw, const float* __restrict__ pw,
    u16* __restrict__ wqkv, u16* __restrict__ pwb)
{
    int i = blockIdx.x * 256 + threadIdx.x;
    if (i < 98304)       wqkv[i] = f2b(qw[i]);
    else if (i < 196608) wqkv[i] = f2b(kw[i - 98304]);
    else if (i < 589824) wqkv[i] = f2b(vw[i - 196608]);
    else if (i < 983040) pwb[i - 589824] = f2b(pw[i - 589824]);
}

// ---------------- prep: x (b,c,n) fp32 -> xb (b*n, c) bf16 ----------------
__global__ __launch_bounds__(256) void k_prep_x(
    const float* __restrict__ x, u16* __restrict__ xb)
{
    __shared__ float t[32][33];
    const int b = blockIdx.z, c0 = blockIdx.y * 32, n0 = blockIdx.x * 32;
    const int tx = threadIdx.x & 31, ty = threadIdx.x >> 5;
    #pragma unroll
    for (int l = 0; l < 4; ++l) {
        int c = c0 + ty + 8 * l, n = n0 + tx;
        t[ty + 8 * l][tx] = (n < NSP) ? x[((long)b * DIM + c) * NSP + n] : 0.f;
    }
    __syncthreads();
    #pragma unroll
    for (int l = 0; l < 4; ++l) {
        int n = n0 + ty + 8 * l, c = c0 + tx;
        if (n < NSP) xb[((long)b * NSP + n) * DIM + c] = f2b(t[tx][ty + 8 * l]);
    }
}

// ---------------- K1: QKV projection (MFMA) ----------------
// A = xb (M = 12544), B = wqkv (N = 1536). grid (98, 12).
__global__ __launch_bounds__(256) void k_qkv(
    const u16* __restrict__ xb, const u16* __restrict__ wqkv,
    const float* __restrict__ qb, const float* __restrict__ kb,
    const float* __restrict__ vb,
    u16* __restrict__ qt, u16* __restrict__ kmat, u16* __restrict__ vt)
{
    __shared__ u16 A_lds[4096], B_lds[4096];
    const int m0 = blockIdx.x * 128, oc0 = blockIdx.y * 128;
    f32x4 acc[4][4];
    gemm128((const char*)xb + (long)m0 * 768, 768,
            (const char*)wqkv + (long)oc0 * 768, 768, 12, A_lds, B_lds, acc);

    const int tid = threadIdx.x, wid = tid >> 6, lane = tid & 63;
    const int wm = (wid & 1) * 64, wn = (wid >> 1) * 64;
    const int col = lane & 15, quad = lane >> 4;
    #pragma unroll
    for (int i = 0; i < 4; ++i) {
        #pragma unroll
        for (int j = 0; j < 4; ++j) {
            #pragma unroll
            for (int r = 0; r < 4; ++r) {
                int m  = m0 + wm + i * 16 + quad * 4 + r;
                int oc = oc0 + wn + j * 16 + col;
                int b = m / NSP, n = m - b * NSP;
                float v = acc[i][j][r];
                if (oc < 256) {
                    qt[(long)m * NQK + oc] = f2b(v + qb[oc]);
                } else if (oc < 512) {
                    int o = oc - 256;
                    kmat[((long)b * NQK + o) * NSP + n] = f2b(v + kb[o]);
                } else {
                    int o = oc - 512, h = o >> 7, d = o & 127;
                    vt[(((long)b * NHD + h) * NSP + n) * DVV + d] = f2b(v + vb[o]);
                }
            }
        }
    }
}

// ---------------- prep: vt -> vtT (bh, d, m) rows padded to 224, pad zeroed --
__global__ __launch_bounds__(256) void k_vtT(
    const u16* __restrict__ vt, u16* __restrict__ vtT)
{
    __shared__ u16 t[32][33];
    const int bh = blockIdx.z, d0 = blockIdx.y * 32, n0 = blockIdx.x * 32;
    const int tx = threadIdx.x & 31, ty = threadIdx.x >> 5;
    #pragma unroll
    for (int l = 0; l < 4; ++l) {
        int n = n0 + ty + 8 * l, d = d0 + tx;
        t[ty + 8 * l][tx] = (n < NSP) ? vt[((long)bh * NSP + n) * DVV + d] : (u16)0;
    }
    __syncthreads();
    #pragma unroll
    for (int l = 0; l < 4; ++l) {
        int d = d0 + ty + 8 * l, m = n0 + tx;
        vtT[((long)bh * DVV + d) * 224 + m] = t[tx][ty + 8 * l];
    }
}

// ---------------- K2: depthwise 3x3 conv ----------------
__global__ __launch_bounds__(256) void k_dwconv(
    const u16* __restrict__ vt, const float* __restrict__ vlw,
    const float* __restrict__ vlb, float* __restrict__ vlt)
{
    int f = blockIdx.x * 256 + threadIdx.x;
    int d  = f & (DVV - 1);
    int t  = f >> 7;
    int n  = t % NSP;
    int bh = t / NSP;
    int h  = bh & 7;
    int y  = n / RES, xx = n - y * RES;
    int ch = h * DVV + d;
    float sacc = vlb[ch];
    const float* wp = vlw + ch * 9;
    const u16* vp = vt + (long)bh * NSP * DVV + d;
    #pragma unroll
    for (int dy = -1; dy <= 1; ++dy) {
        int yy = y + dy;
        if (yy < 0 || yy >= RES) continue;
        #pragma unroll
        for (int dx = -1; dx <= 1; ++dx) {
            int xn = xx + dx;
            if (xn < 0 || xn >= RES) continue;
            sacc += wp[(dy + 1) * 3 + (dx + 1)] * b2f(vp[(yy * RES + xn) * DVV]);
        }
    }
    vlt[f] = sacc;
}

// ---------------- K3: scores + bias + th1 + softmax + th2 ----------------
__global__ __launch_bounds__(256) void k_attn(
    const u16* __restrict__ qt, const u16* __restrict__ kmat,
    const float* __restrict__ bias_seg, const int* __restrict__ bias_idxs,
    const float* __restrict__ th1w, const float* __restrict__ th1b,
    const float* __restrict__ th2w, const float* __restrict__ th2b,
    u16* __restrict__ attn)
{
    __shared__ float qs[4][NQK];
    __shared__ float s[4 * NHD][NSP];
    __shared__ float w1[64], w2[64], b1v[8], b2v[8];
    const int tid = threadIdx.x;
    const int b  = blockIdx.y;
    const int n0 = blockIdx.x * 4;

    if (tid < 64) w1[tid] = th1w[tid];
    else if (tid < 128) w2[tid - 64] = th2w[tid - 64];
    else if (tid < 136) b1v[tid - 128] = th1b[tid - 128];
    else if (tid < 144) b2v[tid - 136] = th2b[tid - 136];

    #pragma unroll
    for (int l = 0; l < 4; ++l) {
        int idx = tid + l * 256;
        int np = idx >> 8, c = idx & 255;
        qs[np][c] = b2f(qt[(long)(b * NSP + n0 + np) * NQK + c]);
    }
    __syncthreads();

    for (int jj = tid; jj < NHD * NSP; jj += 256) {
        int h = jj / NSP;
        int m = jj - h * NSP;
        const u16* kcol = kmat + ((long)b * NQK + h * KDIM) * NSP + m;
        float d0 = 0.f, d1 = 0.f, d2 = 0.f, d3 = 0.f;
        #pragma unroll
        for (int kd = 0; kd < KDIM; ++kd) {
            float kv = b2f(kcol[(long)kd * NSP]);
            d0 += qs[0][h * KDIM + kd] * kv;
            d1 += qs[1][h * KDIM + kd] * kv;
            d2 += qs[2][h * KDIM + kd] * kv;
            d3 += qs[3][h * KDIM + kd] * kv;
        }
        const float* bsh = bias_seg + h * NSP;   // n_off == 196
        s[h][m]      = d0 * SCALE + bsh[bias_idxs[(n0 + 0) * NSP + m]];
        s[8 + h][m]  = d1 * SCALE + bsh[bias_idxs[(n0 + 1) * NSP + m]];
        s[16 + h][m] = d2 * SCALE + bsh[bias_idxs[(n0 + 2) * NSP + m]];
        s[24 + h][m] = d3 * SCALE + bsh[bias_idxs[(n0 + 3) * NSP + m]];
    }
    __syncthreads();

    float regs[4][8];
    {
        int cnt = 0;
        for (int p = tid; p < 4 * NSP; p += 256) {
            int np = p / NSP, m = p - np * NSP;
            #pragma unroll
            for (int g = 0; g < 8; ++g) regs[cnt][g] = s[np * 8 + g][m];
            ++cnt;
        }
        __syncthreads();
        cnt = 0;
        for (int p = tid; p < 4 * NSP; p += 256) {
            int np = p / NSP, m = p - np * NSP;
            #pragma unroll
            for (int h = 0; h < 8; ++h) {
                float a = b1v[h];
                #pragma unroll
                for (int g = 0; g < 8; ++g) a += w1[h * 8 + g] * regs[cnt][g];
                s[np * 8 + h][m] = a;
            }
            ++cnt;
        }
    }
    __syncthreads();

    {
        const int wave = tid >> 6, lane = tid & 63;
        for (int r = wave; r < 32; r += 4) {
            float* row = s[r];
            float mx = -1e30f;
            for (int m = lane; m < NSP; m += 64) mx = fmaxf(mx, row[m]);
            #pragma unroll
            for (int off = 32; off; off >>= 1) mx = fmaxf(mx, __shfl_xor(mx, off));
            float sum = 0.f;
            for (int m = lane; m < NSP; m += 64) {
                float e = __expf(row[m] - mx);
                row[m] = e;
                sum += e;
            }
            #pragma unroll
            for (int off = 32; off; off >>= 1) sum += __shfl_xor(sum, off);
            float inv = 1.0f / sum;
            for (int m = lane; m < NSP; m += 64) row[m] *= inv;
        }
    }
    __syncthreads();

    for (int p = tid; p < 4 * NSP; p += 256) {
        int np = p / NSP, m = p - np * NSP;
        float pg[8];
        #pragma unroll
        for (int g = 0; g < 8; ++g) pg[g] = s[np * 8 + g][m];
        #pragma unroll
        for (int h = 0; h < 8; ++h) {
            float a = b2v[h];
            #pragma unroll
            for (int g = 0; g < 8; ++g) a += w2[h * 8 + g] * pg[g];
            attn[(((long)b * NHD + h) * NSP + n0 + np) * 224 + m] = f2b(a);
        }
    }
}

// ---------------- K4: O = attn @ V (MFMA) + v_local, ReLU ----------------
// per bh: A = attn rows n (stride 224), B = vtT rows d (stride 224), K = 224.
__global__ __launch_bounds__(256) void k_av(
    const u16* __restrict__ attn, const u16* __restrict__ vtT,
    const float* __restrict__ vlt, u16* __restrict__ ot)
{
    __shared__ u16 A_lds[4096], B_lds[4096];
    const int n0 = blockIdx.x * 128;     // 0 or 128
    const int bh = blockIdx.y;
    f32x4 acc[4][4];
    gemm128((const char*)attn + ((long)bh * NSP + n0) * 448, 448,
            (const char*)vtT + (long)bh * DVV * 448, 448, 7, A_lds, B_lds, acc);

    const int tid = threadIdx.x, wid = tid >> 6, lane = tid & 63;
    const int wm = (wid & 1) * 64, wn = (wid >> 1) * 64;
    const int col = lane & 15, quad = lane >> 4;
    const int b = bh >> 3, h = bh & 7;
    #pragma unroll
    for (int i = 0; i < 4; ++i) {
        #pragma unroll
        for (int j = 0; j < 4; ++j) {
            #pragma unroll
            for (int r = 0; r < 4; ++r) {
                int n = n0 + wm + i * 16 + quad * 4 + r;
                int d = wn + j * 16 + col;
                if (n < NSP) {
                    float v = acc[i][j][r] + vlt[((long)bh * NSP + n) * DVV + d];
                    v = fmaxf(v, 0.f);
                    ot[((long)(b * NSP + n)) * 1024 + h * DVV + d] = f2b(v);
                }
            }
        }
    }
}

// ---------------- K5: output projection (MFMA) ----------------
// A = projw (M = 384 oc), B = ot (N = 12544 m). grid (98, 3). out cols = n.
__global__ __launch_bounds__(256) void k_proj(
    const u16* __restrict__ pwb, const u16* __restrict__ ot,
    const float* __restrict__ projb, float* __restrict__ outp)
{
    __shared__ u16 A_lds[4096], B_lds[4096];
    const int m0 = blockIdx.x * 128;     // m (b*n) tile
    const int oc0 = blockIdx.y * 128;    // oc tile
    f32x4 acc[4][4];
    gemm128((const char*)pwb + (long)oc0 * 2048, 2048,
            (const char*)ot + (long)m0 * 2048, 2048, 32, A_lds, B_lds, acc);

    const int tid = threadIdx.x, wid = tid >> 6, lane = tid & 63;
    const int wm = (wid & 1) * 64, wn = (wid >> 1) * 64;
    const int col = lane & 15, quad = lane >> 4;
    #pragma unroll
    for (int i = 0; i < 4; ++i) {
        #pragma unroll
        for (int j = 0; j < 4; ++j) {
            #pragma unroll
            for (int r = 0; r < 4; ++r) {
                int oc = oc0 + wm + i * 16 + quad * 4 + r;
                int mg = m0 + wn + j * 16 + col;
                int b = mg / NSP, n = mg - b * NSP;
                outp[((long)b * DIM + oc) * NSP + n] = acc[i][j][r] + projb[oc];
            }
        }
    }
}

extern "C" void kernel_launch(void* const* d_in, const int* in_sizes, int n_in,
                              void* d_out, int out_size, void* d_ws, size_t ws_size,
                              hipStream_t stream) {
    const float* x        = (const float*)d_in[0];
    const float* qw       = (const float*)d_in[1];
    const float* qb       = (const float*)d_in[2];
    const float* kw       = (const float*)d_in[3];
    const float* kb       = (const float*)d_in[4];
    const float* vw       = (const float*)d_in[5];
    const float* vb       = (const float*)d_in[6];
    const float* vlw      = (const float*)d_in[7];
    const float* vlb      = (const float*)d_in[8];
    const float* th1w     = (const float*)d_in[9];
    const float* th1b     = (const float*)d_in[10];
    const float* th2w     = (const float*)d_in[11];
    const float* th2b     = (const float*)d_in[12];
    const float* projw    = (const float*)d_in[13];
    const float* projb    = (const float*)d_in[14];
    const float* bias_seg = (const float*)d_in[15];
    const int*   bias_idx = (const int*)d_in[16];
    float* outp = (float*)d_out;

    // workspace layout (bytes, all 16B aligned)
    char* w = (char*)d_ws;
    u16* xb    = (u16*)(w);                 // 12544*384        =  9,633,792 B
    u16* wqkv  = (u16*)(w + 9633792);       // 1536*384         =  1,179,648 B
    u16* pwb   = (u16*)(w + 10813440);      // 384*1024         =    786,432 B
    u16* qt    = (u16*)(w + 11599872);      // 12544*256        =  6,422,528 B
    u16* kmat  = (u16*)(w + 18022400);      // 64*256*196       =  6,422,528 B
    u16* vt    = (u16*)(w + 24444928);      // 512*196*128      = 25,690,112 B
    u16* vtT   = (u16*)(w + 50135040);      // 512*128*224      = 29,360,128 B
    u16* attn  = (u16*)(w + 79495168);      // (512*196+64)*224 = 44,986,368 B
    u16* ot    = (u16*)(w + 124481536);     // 12544*1024       = 25,690,112 B
    float* vlt = (float*)(w + 150171648);   // 512*196*128 f32  = 51,380,224 B
    // total 201,551,872 B

    k_prep_w<<<dim3(3840), 256, 0, stream>>>(qw, kw, vw, projw, wqkv, pwb);
    k_prep_x<<<dim3(7, 12, 64), 256, 0, stream>>>(x, xb);
    k_qkv<<<dim3(98, 12), 256, 0, stream>>>(xb, wqkv, qb, kb, vb, qt, kmat, vt);
    k_vtT<<<dim3(7, 4, 512), 256, 0, stream>>>(vt, vtT);
    k_dwconv<<<dim3(50176), 256, 0, stream>>>(vt, vlw, vlb, vlt);
    k_attn<<<dim3(49, 64), 256, 0, stream>>>(qt, kmat, bias_seg, bias_idx,
                                             th1w, th1b, th2w, th2b, attn);
    k_av<<<dim3(2, 512), 256, 0, stream>>>(attn, vtT, vlt, ot);
    k_proj<<<dim3(98, 3), 256, 0, stream>>>(pwb, ot, projb, outp);
}